// Round 5
// baseline (122.681 us; speedup 1.0000x reference)
//
#include <hip/hip_runtime.h>

// BurstSnn: 32-step burst-encoder + 2-layer LIF SNN, B=16384, D=187, H=50, C=5.
// R13 = R12 (67.4us dispatch) + TWO ELEMENTS PER WAVE (A lanes 0-31, B lanes
// 32-63), keeping R11/R12's quarter-wave float4 gather + dense mode:
//  - encoder: 6 regs x 32 lanes per element; one ballot gives both elements'
//    group masks (lo/hi 32b). 2 steps per iter, one gather loop per step over
//    12 same-step masks (6 groups x 2 elements) -> less max-padding than
//    R11's mixed {t,t+1} masks (which the denser step dominated).
//  - LIF1: ONE pass updates both elements (A lanes 0-12, B lanes 32-44) ->
//    halves per-element LIF cost; no cross-half shfls anywhere (cur1 lands on
//    each element's lanes after the xor-16 merge; L2 combine needs 1 shfl).
//  - LIF2/store: one pass, lanes {0-4, 32-36}.
//  - early exit when BOTH elements dead (never earlier than either alone).
// Per element the arithmetic sequence (encoder, group accs, merge order,
// ascending-d ctz, L2 (lo)+(hi) ascending-h, LIF) is identical to R12 ->
// absmax 0.0 by construction. Waves halve: 512 blocks.

constexpr int D = 187;
constexpr int H = 50;
constexpr int C = 5;
constexpr int T = 32;
constexpr int WPB = 16;        // waves per block
constexpr int EPB = WPB * 2;   // elements per block
constexpr int ROWS1 = 193;     // rows rd = 33*(d>>5) + (d&31) + 1; rd=33g zero
constexpr int RS = 64;         // floats per Wt1 row (256 B): 16 float4 slots

__device__ __forceinline__ int v_ffbl(unsigned int m) {  // -1 when m == 0
    int r;
    asm("v_ffbl_b32 %0, %1" : "=v"(r) : "v"(m));
    return r;
}

// acc.x = w.x + acc.x ; acc.y = w.y + acc.y  (one VOP3P instruction)
__device__ __forceinline__ void pk_add(float2& acc, float2 w) {
    asm("v_pk_add_f32 %0, %1, %0" : "+v"(acc) : "v"(w));
}

// m = a*m + c  (per component, fused)
__device__ __forceinline__ void pk_fma(float2& m, float2 a, float2 c) {
    asm("v_pk_fma_f32 %0, %1, %0, %2" : "+v"(m) : "v"(a), "v"(c));
}

// acc = s.lo * w + acc  (scalar broadcast via op_sel_hi)
__device__ __forceinline__ void pk_fma_b(float2& acc, float2 s, float2 w) {
    asm("v_pk_fma_f32 %0, %2, %1, %0 op_sel:[0,0,0] op_sel_hi:[0,1,1]"
        : "+v"(acc) : "v"(w), "v"(s));
}

// lane l <-> l^16 within each 32-lane half (LDS pipe, no VALU)
__device__ __forceinline__ float2 sw16(float2 v) {
    float2 r;
    r.x = __int_as_float(__builtin_amdgcn_ds_swizzle(__float_as_int(v.x), 0x401F));
    r.y = __int_as_float(__builtin_amdgcn_ds_swizzle(__float_as_int(v.y), 0x401F));
    return r;
}

__global__ __launch_bounds__(1024, 8)
void burst_snn_kernel(const float* __restrict__ x,
                      const float* __restrict__ W1,
                      const float* __restrict__ W2,
                      float* __restrict__ out, int B) {
    __shared__ float Wt1[ROWS1 * RS];   // 12352 floats = 48.25 KB
    // Wt2: 64 rows x 16 floats. rows 1..25: h=0..24; rows 27..51: h=25..49.
    __shared__ float Wt2[1024];         // 4 KB

    const int tid = threadIdx.x;
    for (int idx = tid; idx < ROWS1 * RS; idx += 1024) {
        int rd = idx >> 6, j = idx & 63;
        int g = rd / 33;
        bool zrow = (rd == 33 * g);
        int d = rd - 1 - g;
        int slot = j >> 2, c = j & 3;
        int h = 13 * c + slot;
        float v = 0.f;
        if (!zrow && slot < 13 && h < H) v = W1[h * D + d];
        Wt1[idx] = v;
    }
    {
        int r = tid >> 4, c = tid & 15;   // tid covers all 1024
        int h = -1;
        if (r >= 1 && r <= 25) h = r - 1;
        else if (r >= 27 && r <= 51) h = r - 2;
        float v = 0.f;
        if (h >= 0 && c < C) v = W2[c * H + h];
        Wt2[tid] = v;
    }
    __syncthreads();

    const int lane = tid & 63;
    const int laneH = lane & 31;
    const bool isLo = lane < 32;
    const int b = blockIdx.x * EPB + ((tid >> 6) << 1) + (isLo ? 0 : 1);
    const bool active = b < B;
    const int qOdd = (lane >> 4) & 1;    // quarters 1,3 handle odd groups
    const int ql = lane & 15;            // float4 slot within a row (ql<13 live)

    // Gather bases: stream s covers groups {2s (even quarters), 2s+1 (odd)}.
    const char* wb = (const char*)Wt1;
    const int qbase = ql * 16 + (qOdd ? (33 << 8) : 0) + 256;
    const char* bs0 = wb + qbase;               // groups 0/1
    const char* bs1 = wb + qbase + (66 << 8);   // groups 2/3
    const char* bs2 = wb + qbase + (132 << 8);  // groups 4/5

    // L2 quarter scan: quarters scan {loA, hiA, loB, hiB}.
    const float* base2 = Wt2 + ((qOdd ? 27 : 1) << 4) + ql;

    // Encoder registers: element dims 32k + laneH (r5 valid laneH<27)
    float r0 = 0.f, r1 = 0.f, r2 = 0.f, r3 = 0.f, r4 = 0.f, r5 = 0.f;
    if (active) {
        const float* xb = x + (size_t)b * D;
        r0 = xb[laneH];
        r1 = xb[32 + laneH];
        r2 = xb[64 + laneH];
        r3 = xb[96 + laneH];
        r4 = xb[128 + laneH];
        if (laneH < D - 160) r5 = xb[160 + laneH];
    }
    float th0 = 0.125f, th1 = 0.125f, th2 = 0.125f;
    float th3 = 0.125f, th4 = 0.125f, th5 = 0.125f;
    // LIF1 membranes: A lanes 0..12, B lanes 32..44; comps h={ql,13+ql,26+ql,39+ql}
    float2 m01 = make_float2(0.f, 0.f), m23 = make_float2(0.f, 0.f);
    float mem2 = 0.f;                // A lanes 0..4, B lanes 32..36: c = ql
    int cntA = 0, cntB = 0;          // wave-uniform (SALU popcounts)

    const float2 beta2 = make_float2(0.9f, 0.9f);
    const float2 neg1 = make_float2(-1.0f, -1.0f);

    float* outSpk = out;                     // [T][B][C]
    float* outCnt = out + (size_t)T * B * C; // [B]
    const unsigned BC = (unsigned)(B * C);
    unsigned o0 = (unsigned)(b * C + laneH); // only laneH < C stores

    int tDone = T;

    // One step's L1 gather + merge: 12 masks already selected to per-lane vm.
    auto gather = [&](unsigned vm0, unsigned vm1, unsigned vm2, int n,
                      float2& cml, float2& cmh) {
        float2 a0l = {0.f, 0.f}, a0h = {0.f, 0.f};
        float2 a1l = {0.f, 0.f}, a1h = {0.f, 0.f};
        float2 a2l = {0.f, 0.f}, a2h = {0.f, 0.f};
        if (n >= 21) {
            float2 sv0 = {0.f, 0.f}, sv1 = {0.f, 0.f}, sv2 = {0.f, 0.f};
            #pragma unroll
            for (int f = 0; f < 32; ++f) {
                sv0.x = (float)((vm0 >> f) & 1u);
                sv1.x = (float)((vm1 >> f) & 1u);
                sv2.x = (float)((vm2 >> f) & 1u);
                const char* p0 = bs0 + (f << 8);
                const char* p1 = bs1 + (f << 8);
                const char* p2 = bs2 + (f << 8);
                float2 w0l = *(const float2*)p0, w0h = *(const float2*)(p0 + 8);
                float2 w1l = *(const float2*)p1, w1h = *(const float2*)(p1 + 8);
                float2 w2l = *(const float2*)p2, w2h = *(const float2*)(p2 + 8);
                pk_fma_b(a0l, sv0, w0l); pk_fma_b(a0h, sv0, w0h);
                pk_fma_b(a1l, sv1, w1l); pk_fma_b(a1h, sv1, w1h);
                pk_fma_b(a2l, sv2, w2l); pk_fma_b(a2h, sv2, w2h);
            }
        } else {
            for (; n > 0; --n) {
                int f0 = v_ffbl(vm0); vm0 &= vm0 - 1;
                int f1 = v_ffbl(vm1); vm1 &= vm1 - 1;
                int f2 = v_ffbl(vm2); vm2 &= vm2 - 1;
                const char* p0 = bs0 + (f0 << 8);
                const char* p1 = bs1 + (f1 << 8);
                const char* p2 = bs2 + (f2 << 8);
                float2 w0l = *(const float2*)p0, w0h = *(const float2*)(p0 + 8);
                float2 w1l = *(const float2*)p1, w1h = *(const float2*)(p1 + 8);
                float2 w2l = *(const float2*)p2, w2h = *(const float2*)(p2 + 8);
                pk_add(a0l, w0l); pk_add(a0h, w0h);
                pk_add(a1l, w1l); pk_add(a1h, w1h);
                pk_add(a2l, w2l); pk_add(a2h, w2h);
            }
        }
        // merge: odd-group partials to even quarters; order g0..g5 pairwise-left
        float2 s0l = sw16(a0l), s0h = sw16(a0h);
        float2 s1l = sw16(a1l), s1h = sw16(a1h);
        float2 s2l = sw16(a2l), s2h = sw16(a2h);
        cml = a0l; cmh = a0h;
        pk_add(cml, s0l); pk_add(cmh, s0h);   // +g1
        pk_add(cml, a1l); pk_add(cmh, a1h);   // +g2
        pk_add(cml, s1l); pk_add(cmh, s1h);   // +g3
        pk_add(cml, a2l); pk_add(cmh, a2h);   // +g4
        pk_add(cml, s2l); pk_add(cmh, s2h);   // +g5
    };

    // One LIF1 step for BOTH elements; returns h-ordered spike masks.
    auto lif1 = [&](float2 cml, float2 cmh, unsigned& loA, unsigned& hiA,
                    unsigned& loB, unsigned& hiB) {
        pk_fma(m01, beta2, cml);
        pk_fma(m23, beta2, cmh);
        float2 d01 = m01, d23 = m23;
        pk_add(d01, neg1); pk_add(d23, neg1);
        bool t0 = d01.x > 0.f, t1 = d01.y > 0.f;
        bool t2 = d23.x > 0.f, t3 = d23.y > 0.f;
        unsigned long long Pa = __ballot(t0), Pb = __ballot(t1);
        unsigned long long Pc = __ballot(t2), Pd = __ballot(t3);
        m01.x = t0 ? d01.x : m01.x;  m01.y = t1 ? d01.y : m01.y;
        m23.x = t2 ? d23.x : m23.x;  m23.y = t3 ? d23.y : m23.y;
        unsigned cA0 = (unsigned)Pa & 0x1FFFu, cB0 = (unsigned)(Pa >> 32) & 0x1FFFu;
        unsigned cA1 = (unsigned)Pb & 0x1FFFu, cB1 = (unsigned)(Pb >> 32) & 0x1FFFu;
        unsigned cA2 = (unsigned)Pc & 0x1FFFu, cB2 = (unsigned)(Pc >> 32) & 0x1FFFu;
        unsigned cA3 = (unsigned)Pd & 0x1FFFu, cB3 = (unsigned)(Pd >> 32) & 0x1FFFu;
        // h = 13c + l: shift-OR only (SALU)
        loA = cA0 | ((cA1 & 0xFFFu) << 13);
        hiA = (cA1 >> 12) | (cA2 << 1) | ((cA3 & 0x7FFu) << 14);
        loB = cB0 | ((cB1 & 0xFFFu) << 13);
        hiB = (cB1 >> 12) | (cB2 << 1) | ((cB3 & 0x7FFu) << 14);
    };

    // One L2 + LIF2 + store step for BOTH elements.
    auto l2step = [&](unsigned loA, unsigned hiA, unsigned loB, unsigned hiB) {
        int p0 = __popc(loA), p1 = __popc(hiA);
        int p2 = __popc(loB), p3 = __popc(hiB);
        int n2 = p0 > p1 ? p0 : p1;
        n2 = n2 > p2 ? n2 : p2;
        n2 = n2 > p3 ? n2 : p3;
        float cq = 0.f;
        if (n2) {
            unsigned vmq = isLo ? (qOdd ? hiA : loA) : (qOdd ? hiB : loB);
            for (; n2 > 0; --n2) {
                int f = v_ffbl(vmq); vmq &= vmq - 1;
                cq += *(base2 + f * 16);
            }
        }
        // lanes 0..4: A's cur2; lanes 32..36: B's
        float cur2 = cq + __shfl_down(cq, 16);
        mem2 = 0.9f * mem2 + cur2;
        bool sp2 = (mem2 - 1.0f > 0.f);
        mem2 -= sp2 ? 1.0f : 0.f;
        if (active && laneH < C) outSpk[o0] = sp2 ? 1.0f : 0.0f;
        o0 += BC;
    };

    for (int t = 0; t < T; t += 2) {
        // --- encoder step t (exact fp32 sequence); lo32 = A, hi32 = B
        unsigned long long E0, E1, E2, E3, E4, E5;
        {
            bool s0 = r0 >= th0, s1 = r1 >= th1, s2 = r2 >= th2;
            bool s3 = r3 >= th3, s4 = r4 >= th4, s5 = r5 >= th5;
            r0 -= s0 ? th0 : 0.f; th0 = s0 ? th0 + th0 : 0.125f;
            r1 -= s1 ? th1 : 0.f; th1 = s1 ? th1 + th1 : 0.125f;
            r2 -= s2 ? th2 : 0.f; th2 = s2 ? th2 + th2 : 0.125f;
            r3 -= s3 ? th3 : 0.f; th3 = s3 ? th3 + th3 : 0.125f;
            r4 -= s4 ? th4 : 0.f; th4 = s4 ? th4 + th4 : 0.125f;
            r5 -= s5 ? th5 : 0.f; th5 = s5 ? th5 + th5 : 0.125f;
            E0 = __ballot(s0); E1 = __ballot(s1); E2 = __ballot(s2);
            E3 = __ballot(s3); E4 = __ballot(s4); E5 = __ballot(s5);
        }
        // --- encoder step t+1
        unsigned long long F0, F1, F2, F3, F4, F5;
        {
            bool s0 = r0 >= th0, s1 = r1 >= th1, s2 = r2 >= th2;
            bool s3 = r3 >= th3, s4 = r4 >= th4, s5 = r5 >= th5;
            r0 -= s0 ? th0 : 0.f; th0 = s0 ? th0 + th0 : 0.125f;
            r1 -= s1 ? th1 : 0.f; th1 = s1 ? th1 + th1 : 0.125f;
            r2 -= s2 ? th2 : 0.f; th2 = s2 ? th2 + th2 : 0.125f;
            r3 -= s3 ? th3 : 0.f; th3 = s3 ? th3 + th3 : 0.125f;
            r4 -= s4 ? th4 : 0.f; th4 = s4 ? th4 + th4 : 0.125f;
            r5 -= s5 ? th5 : 0.f; th5 = s5 ? th5 + th5 : 0.125f;
            F0 = __ballot(s0); F1 = __ballot(s1); F2 = __ballot(s2);
            F3 = __ballot(s3); F4 = __ballot(s4); F5 = __ballot(s5);
        }

        unsigned At0 = (unsigned)E0, Bt0 = (unsigned)(E0 >> 32);
        unsigned At1 = (unsigned)E1, Bt1 = (unsigned)(E1 >> 32);
        unsigned At2 = (unsigned)E2, Bt2 = (unsigned)(E2 >> 32);
        unsigned At3 = (unsigned)E3, Bt3 = (unsigned)(E3 >> 32);
        unsigned At4 = (unsigned)E4, Bt4 = (unsigned)(E4 >> 32);
        unsigned At5 = (unsigned)E5, Bt5 = (unsigned)(E5 >> 32);
        unsigned Au0 = (unsigned)F0, Bu0 = (unsigned)(F0 >> 32);
        unsigned Au1 = (unsigned)F1, Bu1 = (unsigned)(F1 >> 32);
        unsigned Au2 = (unsigned)F2, Bu2 = (unsigned)(F2 >> 32);
        unsigned Au3 = (unsigned)F3, Bu3 = (unsigned)(F3 >> 32);
        unsigned Au4 = (unsigned)F4, Bu4 = (unsigned)(F4 >> 32);
        unsigned Au5 = (unsigned)F5, Bu5 = (unsigned)(F5 >> 32);

        // SALU: spike counts + per-step trip counts (max of 12 each)
        int qa0 = __popc(At0), qa1 = __popc(At1), qa2 = __popc(At2);
        int qa3 = __popc(At3), qa4 = __popc(At4), qa5 = __popc(At5);
        int qb0 = __popc(Bt0), qb1 = __popc(Bt1), qb2 = __popc(Bt2);
        int qb3 = __popc(Bt3), qb4 = __popc(Bt4), qb5 = __popc(Bt5);
        int ra0 = __popc(Au0), ra1 = __popc(Au1), ra2 = __popc(Au2);
        int ra3 = __popc(Au3), ra4 = __popc(Au4), ra5 = __popc(Au5);
        int rb0 = __popc(Bu0), rb1 = __popc(Bu1), rb2 = __popc(Bu2);
        int rb3 = __popc(Bu3), rb4 = __popc(Bu4), rb5 = __popc(Bu5);
        cntA += qa0 + qa1 + qa2 + qa3 + qa4 + qa5
              + ra0 + ra1 + ra2 + ra3 + ra4 + ra5;
        cntB += qb0 + qb1 + qb2 + qb3 + qb4 + qb5
              + rb0 + rb1 + rb2 + rb3 + rb4 + rb5;
        int nt = qa0 > qa1 ? qa0 : qa1;
        nt = nt > qa2 ? nt : qa2;  nt = nt > qa3 ? nt : qa3;
        nt = nt > qa4 ? nt : qa4;  nt = nt > qa5 ? nt : qa5;
        nt = nt > qb0 ? nt : qb0;  nt = nt > qb1 ? nt : qb1;
        nt = nt > qb2 ? nt : qb2;  nt = nt > qb3 ? nt : qb3;
        nt = nt > qb4 ? nt : qb4;  nt = nt > qb5 ? nt : qb5;
        int nu = ra0 > ra1 ? ra0 : ra1;
        nu = nu > ra2 ? nu : ra2;  nu = nu > ra3 ? nu : ra3;
        nu = nu > ra4 ? nu : ra4;  nu = nu > ra5 ? nu : ra5;
        nu = nu > rb0 ? nu : rb0;  nu = nu > rb1 ? nu : rb1;
        nu = nu > rb2 ? nu : rb2;  nu = nu > rb3 ? nu : rb3;
        nu = nu > rb4 ? nu : rb4;  nu = nu > rb5 ? nu : rb5;

        // Per-lane stream masks for step t: element by isLo, parity by qOdd
        unsigned g0 = isLo ? At0 : Bt0, g1 = isLo ? At1 : Bt1;
        unsigned g2 = isLo ? At2 : Bt2, g3 = isLo ? At3 : Bt3;
        unsigned g4 = isLo ? At4 : Bt4, g5 = isLo ? At5 : Bt5;
        unsigned vmt0 = qOdd ? g1 : g0;
        unsigned vmt1 = qOdd ? g3 : g2;
        unsigned vmt2 = qOdd ? g5 : g4;

        float2 cml, cmh;
        gather(vmt0, vmt1, vmt2, nt, cml, cmh);
        unsigned loAt, hiAt, loBt, hiBt;
        lif1(cml, cmh, loAt, hiAt, loBt, hiBt);

        // step t+1 masks + gather + LIF1
        unsigned h0 = isLo ? Au0 : Bu0, h1 = isLo ? Au1 : Bu1;
        unsigned h2 = isLo ? Au2 : Bu2, h3 = isLo ? Au3 : Bu3;
        unsigned h4 = isLo ? Au4 : Bu4, h5 = isLo ? Au5 : Bu5;
        unsigned vmu0 = qOdd ? h1 : h0;
        unsigned vmu1 = qOdd ? h3 : h2;
        unsigned vmu2 = qOdd ? h5 : h4;

        gather(vmu0, vmu1, vmu2, nu, cml, cmh);
        unsigned loAu, hiAu, loBu, hiBu;
        lif1(cml, cmh, loAu, hiAu, loBu, hiBu);

        // L2 + LIF2 + store, step t then t+1
        l2step(loAt, hiAt, loBt, hiBt);
        l2step(loAu, hiAu, loBu, hiBu);

        // --- early exit: SALU quiet gate, then exact dead check (both elems)
        unsigned long long encAny = E0 | E1 | E2 | E3 | E4 | E5
                                  | F0 | F1 | F2 | F3 | F4 | F5;
        unsigned l1Any = loAt | hiAt | loBt | hiBt
                       | loAu | hiAu | loBu | hiBu;
        if ((encAny | (unsigned long long)l1Any) == 0ull) {
            float rm = fmaxf(fmaxf(fmaxf(r0, r1), fmaxf(r2, r3)), fmaxf(r4, r5));
            unsigned long long am = __ballot(rm >= 0.125f);
            float mm = fmaxf(fmaxf(m01.x, m01.y), fmaxf(m23.x, m23.y));
            unsigned long long m1 = __ballot(mm > 1.0f) & 0x00001FFF00001FFFull;
            unsigned long long m2 = __ballot(mem2 > 1.0f) & 0x0000001F0000001Full;
            if ((am | m1 | m2) == 0ull) { tDone = t + 2; break; }
        }
    }

    // --- zero-fill the provably-silent tail steps
    if (active && laneH < C) {
        for (int tt = tDone; tt < T; ++tt) {
            outSpk[o0] = 0.0f;
            o0 += BC;
        }
    }
    // --- spike counts (wave-uniform SGPRs), one element per half-wave
    if (active && laneH == 0) outCnt[b] = (float)(isLo ? cntA : cntB);
}

extern "C" void kernel_launch(void* const* d_in, const int* in_sizes, int n_in,
                              void* d_out, int out_size, void* d_ws, size_t ws_size,
                              hipStream_t stream) {
    const float* x  = (const float*)d_in[0];
    const float* W1 = (const float*)d_in[1];
    const float* W2 = (const float*)d_in[2];
    float* out = (float*)d_out;
    const int B = in_sizes[0] / D;
    const int blocks = (B + EPB - 1) / EPB;
    burst_snn_kernel<<<blocks, 1024, 0, stream>>>(x, W1, W2, out, B);
}